// Round 1
// baseline (1599.134 us; speedup 1.0000x reference)
//
#include <hip/hip_runtime.h>
#include <stdint.h>

// CGCNN forward. Structure:
//  pre:  CSR sort by dst (hist -> scan -> scatter), permute ef (bf16)
//  emb:  y0 = nf@Wemb ; colstats ; fin ; v = silu(bn(y0))
//  per layer l:
//    ptab:   P_top = v@W[:64], P_mid = v@W[64:128]  (both Wm|Ws concat, 128 cols)
//    edge_mm: y[i] = P_top[src_s] + P_mid[dst_s] + efT@W_bot  (bf16 out + col stats)
//    fin ; aggregate (wave/node, sigmoid*softplus, CSR ranges) ; colstats ; fin
//    v = softplus(bn(agg) + v)
//  pool (atomic) ; readout (3 tiny matmul kernels + 2 stats-fin kernels)
// Biases before BN cancel exactly -> skipped.

#define N_NODES 50000
#define M_EDGES 800000
#define FV 92
#define FE 41
#define EMB 64
#define NL 3
#define EPS 1e-5f

typedef unsigned short u16;
typedef unsigned int u32;

__device__ __forceinline__ float bf2f(u16 u) {
  return __uint_as_float(((u32)u) << 16);
}
__device__ __forceinline__ u16 f2bf(float f) {
  u32 x = __float_as_uint(f);
  return (u16)((x + 0x7fffu + ((x >> 16) & 1u)) >> 16);
}
__device__ __forceinline__ float sigmoidf_(float x) { return 1.0f / (1.0f + __expf(-x)); }
__device__ __forceinline__ float softplusf_(float x) {
  return fmaxf(x, 0.f) + __logf(1.f + __expf(-fabsf(x)));
}
__device__ __forceinline__ float siluf_(float x) { return x * sigmoidf_(x); }

// ---------------- preprocessing ----------------

__global__ void zero_kernel(int* nexts, float* stats, int nInts, int nFloats) {
  int i = blockIdx.x * 256 + threadIdx.x;
  if (i < nInts) nexts[i] = 0;
  if (i < nFloats) stats[i] = 0.f;
}

__global__ void hist_kernel(const int* dst, int* hist) {
  int e = blockIdx.x * 256 + threadIdx.x;
  if (e < M_EDGES) atomicAdd(&hist[dst[e]], 1);
}

__global__ __launch_bounds__(1024) void scan_kernel(int* nexts, int* row_ptr) {
  // single-block exclusive scan of nexts (hist) -> row_ptr and nexts(=copy)
  __shared__ int wsum[16];
  __shared__ int wsoff[16];
  int tid = threadIdx.x;
  int lane = tid & 63, wid = tid >> 6;
  int carry = 0;
  for (int base = 0; base < N_NODES; base += 1024) {
    int i = base + tid;
    int x = (i < N_NODES) ? nexts[i] : 0;
    int v = x;
    #pragma unroll
    for (int off = 1; off < 64; off <<= 1) {
      int nv = __shfl_up(v, off);
      if (lane >= off) v += nv;
    }
    if (lane == 63) wsum[wid] = v;
    __syncthreads();
    if (wid == 0) {
      int w = (lane < 16) ? wsum[lane] : 0;
      #pragma unroll
      for (int off = 1; off < 16; off <<= 1) {
        int nv = __shfl_up(w, off, 16);
        if ((lane & 15) >= off) w += nv;
      }
      if (lane < 16) wsoff[lane] = w;
    }
    __syncthreads();
    int excl = v - x + (wid ? wsoff[wid - 1] : 0) + carry;
    if (i < N_NODES) { row_ptr[i] = excl; nexts[i] = excl; }
    carry += wsoff[15];
    __syncthreads();
  }
  if (tid == 0) row_ptr[N_NODES] = carry;
}

__global__ void scatter_kernel(const int* src, const int* dst, int* nexts,
                               int* pos, int* src_s, int* dst_s) {
  int e = blockIdx.x * 256 + threadIdx.x;
  if (e < M_EDGES) {
    int d = dst[e];
    int p = atomicAdd(&nexts[d], 1);
    pos[e] = p;
    src_s[p] = src[e];
    dst_s[p] = d;
  }
}

__global__ void permute_ef_kernel(const float* ef, const int* pos, u16* ef_s) {
  u32 idx = blockIdx.x * 256 + threadIdx.x;  // exactly M*41
  u32 e = idx / 41u;
  u32 f = idx - e * 41u;
  ef_s[(u32)pos[e] * 41u + f] = f2bf(ef[idx]);
}

// ---------------- embedding ----------------

__global__ void emb_mm_kernel(const float* nf, const float* Wemb, float* y0) {
  __shared__ float Wl[FV][EMB];
  int tid = threadIdx.x;
  for (int idx = tid; idx < FV * EMB; idx += 256) Wl[idx >> 6][idx & 63] = Wemb[idx];
  __syncthreads();
  int t = blockIdx.x * 256 + tid;  // N*16
  int n = t >> 4, q = t & 15;
  const float* row = nf + n * FV;
  float a0 = 0, a1 = 0, a2 = 0, a3 = 0;
  #pragma unroll 4
  for (int k = 0; k < FV; k++) {
    float x = row[k];
    float4 w = *(const float4*)&Wl[k][q * 4];
    a0 = fmaf(x, w.x, a0); a1 = fmaf(x, w.y, a1);
    a2 = fmaf(x, w.z, a2); a3 = fmaf(x, w.w, a3);
  }
  float4 r; r.x = a0; r.y = a1; r.z = a2; r.w = a3;
  *(float4*)&y0[n * EMB + q * 4] = r;
}

__global__ void colstats64_kernel(const float* X, int rows, float* s1, float* s2) {
  int tid = threadIdx.x;
  int c = tid & 63, rl = tid >> 6;
  float sum = 0, ssq = 0;
  for (int r = blockIdx.x * 4 + rl; r < rows; r += gridDim.x * 4) {
    float v = X[r * 64 + c];
    sum += v; ssq += v * v;
  }
  __shared__ float red[4][64][2];
  red[rl][c][0] = sum; red[rl][c][1] = ssq;
  __syncthreads();
  if (tid < 64) {
    atomicAdd(&s1[tid], red[0][tid][0] + red[1][tid][0] + red[2][tid][0] + red[3][tid][0]);
  } else if (tid < 128) {
    int cc = tid - 64;
    atomicAdd(&s2[cc], red[0][cc][1] + red[1][cc][1] + red[2][cc][1] + red[3][cc][1]);
  }
}

__global__ void fin_kernel(const float* s1, const float* s2,
                           const float* g1, const float* b1,
                           const float* g2, const float* b2,
                           float* a, float* c, int C, int half, float minv) {
  int i = threadIdx.x;
  if (i < C) {
    float mean = s1[i] * minv;
    float var = s2[i] * minv - mean * mean;
    float rs = rsqrtf(var + EPS);
    float g = (i < half) ? g1[i] : g2[i - half];
    float b = (i < half) ? b1[i] : b2[i - half];
    float av = g * rs;
    a[i] = av;
    c[i] = b - mean * av;
  }
}

__global__ void emb_apply_kernel(const float* y0, const float* a, const float* c, float* v) {
  int idx = blockIdx.x * 256 + threadIdx.x;  // N*64 exact
  int col = idx & 63;
  v[idx] = siluf_(a[col] * y0[idx] + c[col]);
}

// ---------------- per-layer ----------------

__global__ __launch_bounds__(256) void ptab_kernel(const float* v, const float* Wm_l,
                                                   const float* Ws_l, float* Ptop, float* Pmid) {
  __shared__ float Wl[64][128];
  int tid = threadIdx.x;
  int t = blockIdx.x * 256 + tid;  // N*32
  int n = t >> 5, q = t & 31;
  const float* vr = v + n * 64;
  // phase 1: rows 0..63 (src part)
  for (int idx = tid; idx < 8192; idx += 256) {
    int k = idx >> 7, c = idx & 127;
    Wl[k][c] = (c < 64) ? Wm_l[k * 64 + c] : Ws_l[k * 64 + (c - 64)];
  }
  __syncthreads();
  {
    float a0 = 0, a1 = 0, a2 = 0, a3 = 0;
    #pragma unroll 8
    for (int k = 0; k < 64; k++) {
      float x = vr[k];
      float4 w = *(const float4*)&Wl[k][q * 4];
      a0 = fmaf(x, w.x, a0); a1 = fmaf(x, w.y, a1);
      a2 = fmaf(x, w.z, a2); a3 = fmaf(x, w.w, a3);
    }
    float4 r; r.x = a0; r.y = a1; r.z = a2; r.w = a3;
    *(float4*)&Ptop[n * 128 + q * 4] = r;
  }
  __syncthreads();
  // phase 2: rows 64..127 (dst part)
  for (int idx = tid; idx < 8192; idx += 256) {
    int k = idx >> 7, c = idx & 127;
    Wl[k][c] = (c < 64) ? Wm_l[(64 + k) * 64 + c] : Ws_l[(64 + k) * 64 + (c - 64)];
  }
  __syncthreads();
  {
    float a0 = 0, a1 = 0, a2 = 0, a3 = 0;
    #pragma unroll 8
    for (int k = 0; k < 64; k++) {
      float x = vr[k];
      float4 w = *(const float4*)&Wl[k][q * 4];
      a0 = fmaf(x, w.x, a0); a1 = fmaf(x, w.y, a1);
      a2 = fmaf(x, w.z, a2); a3 = fmaf(x, w.w, a3);
    }
    float4 r; r.x = a0; r.y = a1; r.z = a2; r.w = a3;
    *(float4*)&Pmid[n * 128 + q * 4] = r;
  }
}

// 1250 blocks x 5 tiles x 128 edges = 800000
__global__ __launch_bounds__(256, 3) void edge_mm_kernel(
    const int* src_s, const int* dst_s, const u16* ef_s,
    const float* Ptop, const float* Pmid,
    const float* Wm_l, const float* Ws_l,
    u16* y, float* ys1, float* ys2) {
  __shared__ float Wb[FE][128];    // 21.0 KB : W_bot (rows 128..168 of Wm|Ws)
  __shared__ float efT[FE][132];   // 21.6 KB : transposed ef tile (stride 132 for banks/align)
  int tid = threadIdx.x;
  for (int idx = tid; idx < FE * 128; idx += 256) {
    int f = idx >> 7, c = idx & 127;
    Wb[f][c] = (c < 64) ? Wm_l[(128 + f) * 64 + c] : Ws_l[(128 + f) * 64 + (c - 64)];
  }
  int cg = tid & 31;   // col quad: cols 4cg..4cg+3 of 128
  int eg = tid >> 5;   // edge group: 16 edges each
  float sum4[4] = {0, 0, 0, 0}, ssq4[4] = {0, 0, 0, 0};

  for (int tile = 0; tile < 5; tile++) {
    int T = (blockIdx.x * 5 + tile) * 128;
    __syncthreads();
    for (int j = tid; j < 128 * FE; j += 256) {
      u32 il = (u32)j / 41u;
      u32 f = (u32)j - il * 41u;
      efT[f][il] = bf2f(ef_s[(u32)T * 41u + (u32)j]);
    }
    __syncthreads();

    float acc[16][4];
    #pragma unroll
    for (int e = 0; e < 16; e++) {
      int i = T + eg * 16 + e;
      int s = src_s[i], d = dst_s[i];
      float4 pt = *(const float4*)&Ptop[s * 128 + cg * 4];
      float4 pm = *(const float4*)&Pmid[d * 128 + cg * 4];
      acc[e][0] = pt.x + pm.x; acc[e][1] = pt.y + pm.y;
      acc[e][2] = pt.z + pm.z; acc[e][3] = pt.w + pm.w;
    }
    #pragma unroll 2
    for (int f = 0; f < FE; f++) {
      float4 w = *(const float4*)&Wb[f][cg * 4];
      float4 e0 = *(const float4*)&efT[f][eg * 16 + 0];
      float4 e1 = *(const float4*)&efT[f][eg * 16 + 4];
      float4 e2 = *(const float4*)&efT[f][eg * 16 + 8];
      float4 e3 = *(const float4*)&efT[f][eg * 16 + 12];
      float ev[16] = {e0.x, e0.y, e0.z, e0.w, e1.x, e1.y, e1.z, e1.w,
                      e2.x, e2.y, e2.z, e2.w, e3.x, e3.y, e3.z, e3.w};
      #pragma unroll
      for (int e = 0; e < 16; e++) {
        acc[e][0] = fmaf(ev[e], w.x, acc[e][0]);
        acc[e][1] = fmaf(ev[e], w.y, acc[e][1]);
        acc[e][2] = fmaf(ev[e], w.z, acc[e][2]);
        acc[e][3] = fmaf(ev[e], w.w, acc[e][3]);
      }
    }
    #pragma unroll
    for (int e = 0; e < 16; e++) {
      u32 i = (u32)(T + eg * 16 + e);
      ushort4 pk = make_ushort4(f2bf(acc[e][0]), f2bf(acc[e][1]),
                                f2bf(acc[e][2]), f2bf(acc[e][3]));
      *(ushort4*)&y[i * 128u + (u32)cg * 4u] = pk;
      sum4[0] += acc[e][0]; sum4[1] += acc[e][1]; sum4[2] += acc[e][2]; sum4[3] += acc[e][3];
      ssq4[0] += acc[e][0] * acc[e][0]; ssq4[1] += acc[e][1] * acc[e][1];
      ssq4[2] += acc[e][2] * acc[e][2]; ssq4[3] += acc[e][3] * acc[e][3];
    }
  }
  // block-reduce stats (reuse efT memory: need 2048 floats, have 5412)
  __syncthreads();
  float* red = &efT[0][0];
  #pragma unroll
  for (int j = 0; j < 4; j++) {
    red[eg * 128 + cg * 4 + j] = sum4[j];
    red[1024 + eg * 128 + cg * 4 + j] = ssq4[j];
  }
  __syncthreads();
  if (tid < 128) {
    float s = 0;
    #pragma unroll
    for (int g = 0; g < 8; g++) s += red[g * 128 + tid];
    atomicAdd(&ys1[tid], s);
  } else {
    int cc = tid - 128;
    float s = 0;
    #pragma unroll
    for (int g = 0; g < 8; g++) s += red[1024 + g * 128 + cc];
    atomicAdd(&ys2[cc], s);
  }
}

__global__ void aggregate_kernel(const u16* y, const int* row_ptr,
                                 const float* ya, const float* yc, float* agg) {
  int tid = threadIdx.x;
  int n = blockIdx.x * 4 + (tid >> 6);
  int c = tid & 63;
  float am = ya[c], cm = yc[c], as_ = ya[64 + c], cs = yc[64 + c];
  int i0 = row_ptr[n], i1 = row_ptr[n + 1];
  float acc = 0;
  for (int i = i0; i < i1; i++) {
    float ym = fmaf(am, bf2f(y[(u32)i * 128u + (u32)c]), cm);
    float ysv = fmaf(as_, bf2f(y[(u32)i * 128u + 64u + (u32)c]), cs);
    acc += sigmoidf_(ym) * softplusf_(ysv);
  }
  agg[n * 64 + c] = acc;
}

__global__ void node_update_kernel(const float* agg, const float* na, const float* nc, float* v) {
  int idx = blockIdx.x * 256 + threadIdx.x;  // N*64 exact
  int c = idx & 63;
  v[idx] = softplusf_(na[c] * agg[idx] + nc[c] + v[idx]);
}

// ---------------- pooling + readout ----------------

__global__ void pool_cnt_kernel(const int* gid, float* cnt) {
  int n = blockIdx.x * 256 + threadIdx.x;
  if (n < N_NODES) atomicAdd(&cnt[gid[n]], 1.0f);
}

__global__ void pool_sum_kernel(const float* v, const int* gid, float* sums) {
  int idx = blockIdx.x * 256 + threadIdx.x;  // N*64 exact
  int n = idx >> 6, c = idx & 63;
  atomicAdd(&sums[gid[n] * 64 + c], v[idx]);
}

__global__ void ro_mm1_kernel(const float* psum, const float* pcnt, const float* Wf0, float* y1) {
  int t = blockIdx.x * 256 + threadIdx.x;  // 256*32
  int row = t >> 5, q = t & 31;
  float inv = 1.0f / fmaxf(pcnt[row], 1.0f);
  float a0 = 0, a1 = 0, a2 = 0, a3 = 0;
  #pragma unroll 4
  for (int k = 0; k < 64; k++) {
    float x = psum[row * 64 + k] * inv;
    float4 w = *(const float4*)&Wf0[k * 128 + q * 4];
    a0 = fmaf(x, w.x, a0); a1 = fmaf(x, w.y, a1);
    a2 = fmaf(x, w.z, a2); a3 = fmaf(x, w.w, a3);
  }
  float4 r; r.x = a0; r.y = a1; r.z = a2; r.w = a3;
  *(float4*)&y1[row * 128 + q * 4] = r;
}

__global__ void csfin_kernel(const float* X, int rows, int C,
                             const float* g, const float* b, float* aOut, float* cOut) {
  int c = threadIdx.x;
  if (c < C) {
    float s = 0, ss = 0;
    for (int r = 0; r < rows; r++) {
      float v = X[r * C + c];
      s += v; ss += v * v;
    }
    float inv = 1.0f / (float)rows;
    float mean = s * inv;
    float var = ss * inv - mean * mean;
    float rs = rsqrtf(var + EPS);
    float av = g[c] * rs;
    aOut[c] = av;
    cOut[c] = b[c] - mean * av;
  }
}

__global__ void ro_mm2_kernel(const float* y1, const float* a, const float* c,
                              const float* Wf1, float* y2) {
  int t = blockIdx.x * 256 + threadIdx.x;  // 256*16
  int row = t >> 4, q = t & 15;
  float a0 = 0, a1 = 0, a2 = 0, a3 = 0;
  #pragma unroll 4
  for (int k = 0; k < 128; k++) {
    float act = siluf_(fmaf(a[k], y1[row * 128 + k], c[k]));
    float4 w = *(const float4*)&Wf1[k * 64 + q * 4];
    a0 = fmaf(act, w.x, a0); a1 = fmaf(act, w.y, a1);
    a2 = fmaf(act, w.z, a2); a3 = fmaf(act, w.w, a3);
  }
  float4 r; r.x = a0; r.y = a1; r.z = a2; r.w = a3;
  *(float4*)&y2[row * 64 + q * 4] = r;
}

__global__ void ro_out_kernel(const float* y2, const float* a, const float* c,
                              const float* Wt, const float* bt, float* out) {
  int t = threadIdx.x;  // 256
  float s = bt[0];
  #pragma unroll 4
  for (int cc = 0; cc < 64; cc++)
    s += siluf_(fmaf(a[cc], y2[t * 64 + cc], c[cc])) * Wt[cc];
  out[t] = s;
}

// ---------------- host ----------------

extern "C" void kernel_launch(void* const* d_in, const int* in_sizes, int n_in,
                              void* d_out, int out_size, void* d_ws, size_t ws_size,
                              hipStream_t stream) {
  const float* node_feats = (const float*)d_in[0];
  const float* edge_feats = (const float*)d_in[1];
  const int* src = (const int*)d_in[2];
  const int* dst = (const int*)d_in[3];
  const int* gid = (const int*)d_in[4];
  const float* W_emb = (const float*)d_in[5];
  const float* g_emb = (const float*)d_in[7];
  const float* be_emb = (const float*)d_in[8];
  const float* Wm = (const float*)d_in[9];
  const float* gm = (const float*)d_in[11];
  const float* bem = (const float*)d_in[12];
  const float* Wsc = (const float*)d_in[13];
  const float* gs = (const float*)d_in[15];
  const float* bes = (const float*)d_in[16];
  const float* gn = (const float*)d_in[17];
  const float* ben = (const float*)d_in[18];
  const float* Wf0 = (const float*)d_in[19];
  const float* gf0 = (const float*)d_in[21];
  const float* bef0 = (const float*)d_in[22];
  const float* Wf1 = (const float*)d_in[23];
  const float* gf1 = (const float*)d_in[25];
  const float* bef1 = (const float*)d_in[26];
  const float* Wt = (const float*)d_in[27];
  const float* bt = (const float*)d_in[28];
  float* out = (float*)d_out;

  char* ws = (char*)d_ws;
  size_t off = 0;
  auto alloc = [&](size_t bytes) -> void* {
    void* p = ws + off;
    off = (off + bytes + 511) & ~(size_t)511;
    return p;
  };
  u16* ef_s   = (u16*)alloc((size_t)M_EDGES * 41 * 2);
  u16* ybuf   = (u16*)alloc((size_t)M_EDGES * 128 * 2);
  float* Ptop = (float*)alloc((size_t)N_NODES * 128 * 4);
  float* Pmid = (float*)alloc((size_t)N_NODES * 128 * 4);
  float* vbuf = (float*)alloc((size_t)N_NODES * 64 * 4);
  float* nbuf = (float*)alloc((size_t)N_NODES * 64 * 4);
  int* row_ptr = (int*)alloc((size_t)(N_NODES + 1) * 4);
  int* nexts   = (int*)alloc((size_t)N_NODES * 4);
  int* pos     = (int*)alloc((size_t)M_EDGES * 4);
  int* src_s   = (int*)alloc((size_t)M_EDGES * 4);
  int* dst_s   = (int*)alloc((size_t)M_EDGES * 4);
  float* stats = (float*)alloc((size_t)68736 * 4);
  (void)ws_size; (void)in_sizes; (void)n_in; (void)out_size;

  // stats region offsets (floats)
  float* emb_s1 = stats + 0;
  float* emb_s2 = stats + 64;
  float* emb_a  = stats + 128;
  float* emb_c  = stats + 192;
  float* ys1    = stats + 256;   // 3*128
  float* ys2    = stats + 640;
  float* ya     = stats + 1024;
  float* yc     = stats + 1408;
  float* as1    = stats + 1792;  // 3*64
  float* as2    = stats + 1984;
  float* na     = stats + 2176;
  float* nc     = stats + 2368;
  float* pcnt   = stats + 2560;  // 256
  float* psum   = stats + 2816;  // 256*64
  float* aff0a  = stats + 19200;
  float* aff0c  = stats + 19328;
  float* aff1a  = stats + 19456;
  float* aff1c  = stats + 19520;
  float* rb1    = stats + 19584;  // 256*128
  float* rb2    = stats + 52352;  // 256*64

  // preprocessing
  zero_kernel<<<196, 256, 0, stream>>>(nexts, stats, N_NODES, 19200);
  hist_kernel<<<3125, 256, 0, stream>>>(dst, nexts);
  scan_kernel<<<1, 1024, 0, stream>>>(nexts, row_ptr);
  scatter_kernel<<<3125, 256, 0, stream>>>(src, dst, nexts, pos, src_s, dst_s);
  permute_ef_kernel<<<128125, 256, 0, stream>>>(edge_feats, pos, ef_s);
  pool_cnt_kernel<<<196, 256, 0, stream>>>(gid, pcnt);

  // embedding
  emb_mm_kernel<<<3125, 256, 0, stream>>>(node_feats, W_emb, nbuf);
  colstats64_kernel<<<200, 256, 0, stream>>>(nbuf, N_NODES, emb_s1, emb_s2);
  fin_kernel<<<1, 128, 0, stream>>>(emb_s1, emb_s2, g_emb, be_emb, g_emb, be_emb,
                                    emb_a, emb_c, 64, 64, 1.0f / N_NODES);
  emb_apply_kernel<<<12500, 256, 0, stream>>>(nbuf, emb_a, emb_c, vbuf);

  for (int l = 0; l < NL; l++) {
    const float* Wm_l = Wm + (size_t)l * 169 * 64;
    const float* Ws_l = Wsc + (size_t)l * 169 * 64;
    ptab_kernel<<<6250, 256, 0, stream>>>(vbuf, Wm_l, Ws_l, Ptop, Pmid);
    edge_mm_kernel<<<1250, 256, 0, stream>>>(src_s, dst_s, ef_s, Ptop, Pmid,
                                             Wm_l, Ws_l, ybuf,
                                             ys1 + l * 128, ys2 + l * 128);
    fin_kernel<<<1, 128, 0, stream>>>(ys1 + l * 128, ys2 + l * 128,
                                      gm + l * 64, bem + l * 64, gs + l * 64, bes + l * 64,
                                      ya + l * 128, yc + l * 128, 128, 64, 1.0f / M_EDGES);
    aggregate_kernel<<<12500, 256, 0, stream>>>(ybuf, row_ptr, ya + l * 128, yc + l * 128, nbuf);
    colstats64_kernel<<<200, 256, 0, stream>>>(nbuf, N_NODES, as1 + l * 64, as2 + l * 64);
    fin_kernel<<<1, 128, 0, stream>>>(as1 + l * 64, as2 + l * 64,
                                      gn + l * 64, ben + l * 64, gn + l * 64, ben + l * 64,
                                      na + l * 64, nc + l * 64, 64, 64, 1.0f / N_NODES);
    node_update_kernel<<<12500, 256, 0, stream>>>(nbuf, na + l * 64, nc + l * 64, vbuf);
  }

  // pooling + readout
  pool_sum_kernel<<<12500, 256, 0, stream>>>(vbuf, gid, psum);
  ro_mm1_kernel<<<32, 256, 0, stream>>>(psum, pcnt, Wf0, rb1);
  csfin_kernel<<<1, 128, 0, stream>>>(rb1, 256, 128, gf0, bef0, aff0a, aff0c);
  ro_mm2_kernel<<<16, 256, 0, stream>>>(rb1, aff0a, aff0c, Wf1, rb2);
  csfin_kernel<<<1, 128, 0, stream>>>(rb2, 256, 64, gf1, bef1, aff1a, aff1c);
  ro_out_kernel<<<1, 256, 0, stream>>>(rb2, aff1a, aff1c, Wt, bt, out);
}

// Round 2
// 1327.153 us; speedup vs baseline: 1.2049x; 1.2049x over previous
//
#include <hip/hip_runtime.h>
#include <stdint.h>

// CGCNN forward, round 2: MFMA edge_mm + launch fusion.
//  pre:  CSR sort by dst (hist -> 3-kernel scan -> scatter), gather-permute ef (bf16, padded 48)
//  emb:  y0 = nf@Wemb ; colstats ; v = silu(bn(y0))          (fin fused into apply)
//  per layer l:
//    ptab:    P_top/P_mid = v@W halves  -> bf16 tables
//    edge_mm: G = efT@Wbot via mfma_32x32x16_bf16 (K=48), epilogue adds gathered P,
//             writes y bf16 + column stats. XCD-swizzled blocks keep Pmid L2-local.
//    aggregate(+fin): CSR wave-per-node sigmoid*softplus sum
//    colstats ; node_update(+fin): v = softplus(bn(agg)+v)
//  pool_sum: run-length (gid sorted) -> psum/pcnt ; readout: 3 kernels, stats inlined.
// Biases before BN cancel exactly -> skipped.

#define N_NODES 50000
#define M_EDGES 800000
#define FV 92
#define FE 41
#define EMB 64
#define NL 3
#define EPS 1e-5f

typedef unsigned short u16;
typedef unsigned int u32;
typedef __attribute__((ext_vector_type(8))) short bf16x8;
typedef __attribute__((ext_vector_type(16))) float f32x16;

__device__ __forceinline__ float bf2f(u16 u) {
  return __uint_as_float(((u32)u) << 16);
}
__device__ __forceinline__ u16 f2bf(float f) {
  u32 x = __float_as_uint(f);
  return (u16)((x + 0x7fffu + ((x >> 16) & 1u)) >> 16);
}
__device__ __forceinline__ float sigmoidf_(float x) { return 1.0f / (1.0f + __expf(-x)); }
__device__ __forceinline__ float softplusf_(float x) {
  return fmaxf(x, 0.f) + __logf(1.f + __expf(-fabsf(x)));
}
__device__ __forceinline__ float siluf_(float x) { return x * sigmoidf_(x); }

// ---------------- preprocessing ----------------

__global__ void zero_kernel(int* nexts, float* stats, int nInts, int nFloats) {
  int i = blockIdx.x * 256 + threadIdx.x;
  if (i < nInts) nexts[i] = 0;
  if (i < nFloats) stats[i] = 0.f;
}

__global__ void hist_kernel(const int* dst, int* hist) {
  int e = blockIdx.x * 256 + threadIdx.x;
  if (e < M_EDGES) atomicAdd(&hist[dst[e]], 1);
}

__global__ void scanA_kernel(const int* hist, int* bsum) {
  int tid = threadIdx.x;
  int i = blockIdx.x * 256 + tid;
  int x = (i < N_NODES) ? hist[i] : 0;
  #pragma unroll
  for (int o = 32; o > 0; o >>= 1) x += __shfl_xor(x, o);
  __shared__ int wsm[4];
  if ((tid & 63) == 0) wsm[tid >> 6] = x;
  __syncthreads();
  if (tid == 0) bsum[blockIdx.x] = wsm[0] + wsm[1] + wsm[2] + wsm[3];
}

__global__ void scanB_kernel(const int* bsum, int* boffs, int* row_ptr) {
  int tid = threadIdx.x;
  int lane = tid & 63, wid = tid >> 6;
  int x = (tid < 196) ? bsum[tid] : 0;
  int v = x;
  #pragma unroll
  for (int o = 1; o < 64; o <<= 1) {
    int nv = __shfl_up(v, o);
    if (lane >= o) v += nv;
  }
  __shared__ int wsm[4];
  if (lane == 63) wsm[wid] = v;
  __syncthreads();
  int add = 0;
  for (int wq = 0; wq < wid; wq++) add += wsm[wq];
  if (tid < 196) boffs[tid] = v + add - x;  // exclusive
  if (tid == 0) row_ptr[N_NODES] = M_EDGES;
}

__global__ void scanC_kernel(const int* hist, const int* boffs, int* row_ptr, int* nexts) {
  int tid = threadIdx.x;
  int i = blockIdx.x * 256 + tid;
  int lane = tid & 63, wid = tid >> 6;
  int x = (i < N_NODES) ? hist[i] : 0;
  int v = x;
  #pragma unroll
  for (int o = 1; o < 64; o <<= 1) {
    int nv = __shfl_up(v, o);
    if (lane >= o) v += nv;
  }
  __shared__ int wsm[4];
  if (lane == 63) wsm[wid] = v;
  __syncthreads();
  int add = boffs[blockIdx.x];
  for (int wq = 0; wq < wid; wq++) add += wsm[wq];
  int excl = v - x + add;
  if (i < N_NODES) { row_ptr[i] = excl; nexts[i] = excl; }
}

__global__ void scatter_kernel(const int* src, const int* dst, int* nexts,
                               int* eid_s, int* src_s, int* dst_s) {
  int e = blockIdx.x * 256 + threadIdx.x;
  if (e < M_EDGES) {
    int d = dst[e];
    int p = atomicAdd(&nexts[d], 1);
    eid_s[p] = e;
    src_s[p] = src[e];
    dst_s[p] = d;
  }
}

// gather-direction permute: coalesced writes, padded to 48 cols with zeros
__global__ void permute_ef_kernel(const float* ef, const int* eid_s, u16* ef_s) {
  int tid = threadIdx.x;
  u32 p = blockIdx.x * 32 + (tid >> 3);  // 25000 blocks * 32 rows = M
  int q = tid & 7;
  int e = eid_s[p];
  const float* base = ef + (size_t)e * 41;
  u32* orow = (u32*)ef_s + (size_t)p * 24 + q * 3;
  #pragma unroll
  for (int i = 0; i < 3; i++) {
    int k = q * 6 + i * 2;
    float lo = (k < 41) ? base[k] : 0.f;
    float hi = (k + 1 < 41) ? base[k + 1] : 0.f;
    orow[i] = (u32)f2bf(lo) | ((u32)f2bf(hi) << 16);
  }
}

// ---------------- embedding ----------------

__global__ void emb_mm_kernel(const float* nf, const float* Wemb, float* y0) {
  __shared__ float Wl[FV][EMB];
  int tid = threadIdx.x;
  for (int idx = tid; idx < FV * EMB; idx += 256) Wl[idx >> 6][idx & 63] = Wemb[idx];
  __syncthreads();
  int t = blockIdx.x * 256 + tid;  // N*16
  int n = t >> 4, q = t & 15;
  const float* row = nf + n * FV;
  float a0 = 0, a1 = 0, a2 = 0, a3 = 0;
  #pragma unroll 4
  for (int k = 0; k < FV; k++) {
    float x = row[k];
    float4 w = *(const float4*)&Wl[k][q * 4];
    a0 = fmaf(x, w.x, a0); a1 = fmaf(x, w.y, a1);
    a2 = fmaf(x, w.z, a2); a3 = fmaf(x, w.w, a3);
  }
  float4 r; r.x = a0; r.y = a1; r.z = a2; r.w = a3;
  *(float4*)&y0[n * EMB + q * 4] = r;
}

__global__ void colstats64_kernel(const float* X, int rows, float* s1, float* s2) {
  int tid = threadIdx.x;
  int c = tid & 63, rl = tid >> 6;
  float sum = 0, ssq = 0;
  for (int r = blockIdx.x * 4 + rl; r < rows; r += gridDim.x * 4) {
    float v = X[r * 64 + c];
    sum += v; ssq += v * v;
  }
  __shared__ float red[4][64][2];
  red[rl][c][0] = sum; red[rl][c][1] = ssq;
  __syncthreads();
  if (tid < 64) {
    atomicAdd(&s1[tid], red[0][tid][0] + red[1][tid][0] + red[2][tid][0] + red[3][tid][0]);
  } else if (tid < 128) {
    int cc = tid - 64;
    atomicAdd(&s2[cc], red[0][cc][1] + red[1][cc][1] + red[2][cc][1] + red[3][cc][1]);
  }
}

__global__ void emb_apply_kernel(const float* y0, const float* s1, const float* s2,
                                 const float* g, const float* be, float* v) {
  __shared__ float aS[64], cS[64];
  int tid = threadIdx.x;
  if (tid < 64) {
    float mean = s1[tid] * (1.0f / N_NODES);
    float var = s2[tid] * (1.0f / N_NODES) - mean * mean;
    float av = g[tid] * rsqrtf(var + EPS);
    aS[tid] = av; cS[tid] = be[tid] - mean * av;
  }
  __syncthreads();
  int idx = blockIdx.x * 256 + tid;  // N*64 exact
  int col = idx & 63;
  v[idx] = siluf_(aS[col] * y0[idx] + cS[col]);
}

// ---------------- per-layer ----------------

__global__ __launch_bounds__(256) void ptab_kernel(const float* v, const float* Wm_l,
                                                   const float* Ws_l, u16* Ptop, u16* Pmid) {
  __shared__ float Wl[64][128];
  int tid = threadIdx.x;
  int t = blockIdx.x * 256 + tid;  // N*32
  int n = t >> 5, q = t & 31;
  const float* vr = v + n * 64;
  // phase 1: rows 0..63 (src part)
  for (int idx = tid; idx < 8192; idx += 256) {
    int k = idx >> 7, c = idx & 127;
    Wl[k][c] = (c < 64) ? Wm_l[k * 64 + c] : Ws_l[k * 64 + (c - 64)];
  }
  __syncthreads();
  {
    float a0 = 0, a1 = 0, a2 = 0, a3 = 0;
    #pragma unroll 8
    for (int k = 0; k < 64; k++) {
      float x = vr[k];
      float4 w = *(const float4*)&Wl[k][q * 4];
      a0 = fmaf(x, w.x, a0); a1 = fmaf(x, w.y, a1);
      a2 = fmaf(x, w.z, a2); a3 = fmaf(x, w.w, a3);
    }
    ((ushort4*)Ptop)[(size_t)n * 32 + q] =
        make_ushort4(f2bf(a0), f2bf(a1), f2bf(a2), f2bf(a3));
  }
  __syncthreads();
  // phase 2: rows 64..127 (dst part)
  for (int idx = tid; idx < 8192; idx += 256) {
    int k = idx >> 7, c = idx & 127;
    Wl[k][c] = (c < 64) ? Wm_l[(64 + k) * 64 + c] : Ws_l[(64 + k) * 64 + (c - 64)];
  }
  __syncthreads();
  {
    float a0 = 0, a1 = 0, a2 = 0, a3 = 0;
    #pragma unroll 8
    for (int k = 0; k < 64; k++) {
      float x = vr[k];
      float4 w = *(const float4*)&Wl[k][q * 4];
      a0 = fmaf(x, w.x, a0); a1 = fmaf(x, w.y, a1);
      a2 = fmaf(x, w.z, a2); a3 = fmaf(x, w.w, a3);
    }
    ((ushort4*)Pmid)[(size_t)n * 32 + q] =
        make_ushort4(f2bf(a0), f2bf(a1), f2bf(a2), f2bf(a3));
  }
}

// MFMA edge kernel: 1250 blocks x 5 tiles x 128 edges.
// Per tile: G[128x128] = ef[128x48]@Wbot[48x128] via 32x32x16 bf16 MFMA,
// then per 64-edge half: spill C->LDS f32, edge-major epilogue adds gathered
// bf16 P tables, packs y bf16, accumulates column stats.
__global__ __launch_bounds__(256, 2) void edge_mm_kernel(
    const int* __restrict__ src_s, const int* __restrict__ dst_s,
    const u16* __restrict__ ef_s,
    const u16* __restrict__ Ptop, const u16* __restrict__ Pmid,
    const float* __restrict__ Wm_l, const float* __restrict__ Ws_l,
    u16* __restrict__ y, float* __restrict__ ys1, float* __restrict__ ys2) {
  __shared__ u16 WbF[6144];        // B frags, linear: [(t*3+ks)*64+lane]*8, 12 KB
  __shared__ float yb[64 * 132];   // C spill half-tile, 33.8 KB
  int tid = threadIdx.x;
  int w = tid >> 6, lane = tid & 63;
  int l31 = lane & 31, lh = lane >> 5;

  // bijective XCD swizzle: each XCD gets a contiguous (dst-sorted) chunk
  int nwg = gridDim.x;
  int q = nwg >> 3, r = nwg & 7;
  int xcd = blockIdx.x & 7, bidx = blockIdx.x >> 3;
  int bswz = (xcd < r ? xcd * (q + 1) : r * (q + 1) + (xcd - r) * q) + bidx;

  // stage Wbot as B fragments (col = 32t+(ln&31), k = ks*16+(ln>>5)*8+j)
  for (int t = tid; t < 6144; t += 256) {
    int slot = t >> 3, j = t & 7;
    int tt = slot / 192, rem = slot - tt * 192;
    int ks = rem >> 6, ln = rem & 63;
    int col = tt * 32 + (ln & 31);
    int k = ks * 16 + ((ln >> 5) << 3) + j;
    float val = 0.f;
    if (k < FE) val = (col < 64) ? Wm_l[(128 + k) * 64 + col] : Ws_l[(128 + k) * 64 + (col - 64)];
    WbF[t] = f2bf(val);
  }
  __syncthreads();

  float sum4[4] = {0, 0, 0, 0}, ssq4[4] = {0, 0, 0, 0};
  int cgE = tid & 31, egE = tid >> 5;

  for (int tile = 0; tile < 5; tile++) {
    int T = (bswz * 5 + tile) * 128;
    // A frags: this wave's 32 edge rows, straight from global (padded 48-col ef)
    const u16* ap = ef_s + (size_t)(T + 32 * w + l31) * 48 + lh * 8;
    bf16x8 a0 = *(const bf16x8*)(ap);
    bf16x8 a1 = *(const bf16x8*)(ap + 16);
    bf16x8 a2 = *(const bf16x8*)(ap + 32);
    f32x16 acc0, acc1, acc2, acc3;
    #pragma unroll
    for (int i = 0; i < 16; i++) { acc0[i] = 0.f; acc1[i] = 0.f; acc2[i] = 0.f; acc3[i] = 0.f; }
    #pragma unroll
    for (int ks = 0; ks < 3; ks++) {
      bf16x8 a = (ks == 0) ? a0 : (ks == 1) ? a1 : a2;
      bf16x8 b0 = *(const bf16x8*)&WbF[((0 * 3 + ks) * 64 + lane) * 8];
      bf16x8 b1 = *(const bf16x8*)&WbF[((1 * 3 + ks) * 64 + lane) * 8];
      bf16x8 b2 = *(const bf16x8*)&WbF[((2 * 3 + ks) * 64 + lane) * 8];
      bf16x8 b3 = *(const bf16x8*)&WbF[((3 * 3 + ks) * 64 + lane) * 8];
      acc0 = __builtin_amdgcn_mfma_f32_32x32x16_bf16(a, b0, acc0, 0, 0, 0);
      acc1 = __builtin_amdgcn_mfma_f32_32x32x16_bf16(a, b1, acc1, 0, 0, 0);
      acc2 = __builtin_amdgcn_mfma_f32_32x32x16_bf16(a, b2, acc2, 0, 0, 0);
      acc3 = __builtin_amdgcn_mfma_f32_32x32x16_bf16(a, b3, acc3, 0, 0, 0);
    }
    #pragma unroll
    for (int h = 0; h < 2; h++) {
      __syncthreads();  // yb free (previous epilogue finished)
      if ((w >> 1) == h) {
        int eb = 32 * (w & 1);
        #pragma unroll
        for (int rg = 0; rg < 16; rg++) {
          int row = (rg & 3) + 8 * (rg >> 2) + 4 * lh;  // C/D layout (m74/m101)
          float* yr = &yb[(eb + row) * 132 + l31];
          yr[0]  = acc0[rg];
          yr[32] = acc1[rg];
          yr[64] = acc2[rg];
          yr[96] = acc3[rg];
        }
      }
      __syncthreads();
      // edge-major epilogue on edges [h*64, h*64+64)
      #pragma unroll
      for (int ei = 0; ei < 8; ei++) {
        int el = egE * 8 + ei;
        int i = T + h * 64 + el;
        float4 g4 = *(const float4*)&yb[el * 132 + cgE * 4];
        int s = src_s[i], d = dst_s[i];
        ushort4 pt = ((const ushort4*)Ptop)[(size_t)s * 32 + cgE];
        ushort4 pm = ((const ushort4*)Pmid)[(size_t)d * 32 + cgE];
        float y0v = g4.x + bf2f(pt.x) + bf2f(pm.x);
        float y1v = g4.y + bf2f(pt.y) + bf2f(pm.y);
        float y2v = g4.z + bf2f(pt.z) + bf2f(pm.z);
        float y3v = g4.w + bf2f(pt.w) + bf2f(pm.w);
        ((ushort4*)y)[(size_t)i * 32 + cgE] =
            make_ushort4(f2bf(y0v), f2bf(y1v), f2bf(y2v), f2bf(y3v));
        sum4[0] += y0v; sum4[1] += y1v; sum4[2] += y2v; sum4[3] += y3v;
        ssq4[0] += y0v * y0v; ssq4[1] += y1v * y1v;
        ssq4[2] += y2v * y2v; ssq4[3] += y3v * y3v;
      }
    }
  }
  // block-reduce stats (reuse yb: 2048 floats needed)
  __syncthreads();
  float* red = yb;
  #pragma unroll
  for (int j = 0; j < 4; j++) {
    red[egE * 128 + cgE * 4 + j] = sum4[j];
    red[1024 + egE * 128 + cgE * 4 + j] = ssq4[j];
  }
  __syncthreads();
  if (tid < 128) {
    float s = 0;
    #pragma unroll
    for (int g = 0; g < 8; g++) s += red[g * 128 + tid];
    atomicAdd(&ys1[tid], s);
  } else {
    int cc = tid - 128;
    float s = 0;
    #pragma unroll
    for (int g = 0; g < 8; g++) s += red[1024 + g * 128 + cc];
    atomicAdd(&ys2[cc], s);
  }
}

__global__ void aggregate_kernel(const u16* __restrict__ y, const int* __restrict__ row_ptr,
                                 const float* ys1, const float* ys2,
                                 const float* gm_l, const float* bem_l,
                                 const float* gs_l, const float* bes_l, float* agg) {
  __shared__ float aS[128], cS[128];
  int tid = threadIdx.x;
  if (tid < 128) {
    float mean = ys1[tid] * (1.0f / M_EDGES);
    float var = ys2[tid] * (1.0f / M_EDGES) - mean * mean;
    float g = (tid < 64) ? gm_l[tid] : gs_l[tid - 64];
    float b = (tid < 64) ? bem_l[tid] : bes_l[tid - 64];
    float av = g * rsqrtf(var + EPS);
    aS[tid] = av; cS[tid] = b - mean * av;
  }
  __syncthreads();
  int n = blockIdx.x * 4 + (tid >> 6);
  int c = tid & 63;
  float am = aS[c], cm = cS[c], as_ = aS[64 + c], cs = cS[64 + c];
  int i0 = row_ptr[n], i1 = row_ptr[n + 1];
  float acc = 0;
  for (int i = i0; i < i1; i++) {
    float ym = fmaf(am, bf2f(y[(size_t)i * 128 + c]), cm);
    float ysv = fmaf(as_, bf2f(y[(size_t)i * 128 + 64 + c]), cs);
    acc += sigmoidf_(ym) * softplusf_(ysv);
  }
  agg[n * 64 + c] = acc;
}

__global__ void node_update_kernel(const float* agg, const float* s1, const float* s2,
                                   const float* gn_l, const float* ben_l, float* v) {
  __shared__ float aS[64], cS[64];
  int tid = threadIdx.x;
  if (tid < 64) {
    float mean = s1[tid] * (1.0f / N_NODES);
    float var = s2[tid] * (1.0f / N_NODES) - mean * mean;
    float av = gn_l[tid] * rsqrtf(var + EPS);
    aS[tid] = av; cS[tid] = ben_l[tid] - mean * av;
  }
  __syncthreads();
  int idx = blockIdx.x * 256 + tid;  // N*64 exact
  int c = idx & 63;
  v[idx] = softplusf_(aS[c] * agg[idx] + cS[c] + v[idx]);
}

// ---------------- pooling + readout ----------------

// gid is sorted: run-length accumulate per wave (wave = 64 lanes = 64 cols)
__global__ void pool_sum_kernel(const float* v, const int* gid, float* psum, float* pcnt) {
  int tid = threadIdx.x;
  int g = blockIdx.x * 4 + (tid >> 6);
  int lane = tid & 63;
  int n0 = g * 64;
  if (n0 >= N_NODES) return;
  int n1 = min(n0 + 64, N_NODES);
  int cur = gid[n0];
  float acc = 0;
  int runlen = 0;
  for (int n = n0; n < n1; n++) {
    int gg = gid[n];
    if (gg != cur) {
      atomicAdd(&psum[cur * 64 + lane], acc);
      if (lane == 0) atomicAdd(&pcnt[cur], (float)runlen);
      acc = 0; runlen = 0; cur = gg;
    }
    acc += v[n * 64 + lane];
    runlen++;
  }
  atomicAdd(&psum[cur * 64 + lane], acc);
  if (lane == 0) atomicAdd(&pcnt[cur], (float)runlen);
}

__global__ void ro_mm1_kernel(const float* psum, const float* pcnt, const float* Wf0, float* y1) {
  int t = blockIdx.x * 256 + threadIdx.x;  // 256*32
  int row = t >> 5, q = t & 31;
  float inv = 1.0f / fmaxf(pcnt[row], 1.0f);
  float a0 = 0, a1 = 0, a2 = 0, a3 = 0;
  #pragma unroll 4
  for (int k = 0; k < 64; k++) {
    float x = psum[row * 64 + k] * inv;
    float4 w = *(const float4*)&Wf0[k * 128 + q * 4];
    a0 = fmaf(x, w.x, a0); a1 = fmaf(x, w.y, a1);
    a2 = fmaf(x, w.z, a2); a3 = fmaf(x, w.w, a3);
  }
  float4 r; r.x = a0; r.y = a1; r.z = a2; r.w = a3;
  *(float4*)&y1[row * 128 + q * 4] = r;
}

__global__ void ro_mm2_kernel(const float* y1, const float* gf0, const float* bef0,
                              const float* Wf1, float* y2) {
  __shared__ float aS[128], cS[128], pS[2][128], pQ[2][128];
  int tid = threadIdx.x;
  int c = tid & 127, h = tid >> 7;
  float s = 0, ss = 0;
  for (int rr = h * 128; rr < h * 128 + 128; rr++) {
    float x = y1[rr * 128 + c];
    s += x; ss += x * x;
  }
  pS[h][c] = s; pQ[h][c] = ss;
  __syncthreads();
  if (tid < 128) {
    float S = pS[0][tid] + pS[1][tid], Q = pQ[0][tid] + pQ[1][tid];
    float mean = S * (1.0f / 256.0f), var = Q * (1.0f / 256.0f) - mean * mean;
    float av = gf0[tid] * rsqrtf(var + EPS);
    aS[tid] = av; cS[tid] = bef0[tid] - mean * av;
  }
  __syncthreads();
  int t = blockIdx.x * 256 + tid;  // 256*16
  int row = t >> 4, q = t & 15;
  float a0 = 0, a1 = 0, a2 = 0, a3 = 0;
  #pragma unroll 4
  for (int k = 0; k < 128; k++) {
    float act = siluf_(fmaf(aS[k], y1[row * 128 + k], cS[k]));
    float4 w = *(const float4*)&Wf1[k * 64 + q * 4];
    a0 = fmaf(act, w.x, a0); a1 = fmaf(act, w.y, a1);
    a2 = fmaf(act, w.z, a2); a3 = fmaf(act, w.w, a3);
  }
  float4 r; r.x = a0; r.y = a1; r.z = a2; r.w = a3;
  *(float4*)&y2[row * 64 + q * 4] = r;
}

__global__ void ro_out_kernel(const float* y2, const float* gf1, const float* bef1,
                              const float* Wt, const float* bt, float* out) {
  __shared__ float aS[64], cS[64], pS[4][64], pQ[4][64];
  int tid = threadIdx.x;
  int c = tid & 63, h = tid >> 6;
  float s = 0, ss = 0;
  for (int rr = h * 64; rr < h * 64 + 64; rr++) {
    float x = y2[rr * 64 + c];
    s += x; ss += x * x;
  }
  pS[h][c] = s; pQ[h][c] = ss;
  __syncthreads();
  if (tid < 64) {
    float S = pS[0][tid] + pS[1][tid] + pS[2][tid] + pS[3][tid];
    float Q = pQ[0][tid] + pQ[1][tid] + pQ[2][tid] + pQ[3][tid];
    float mean = S * (1.0f / 256.0f), var = Q * (1.0f / 256.0f) - mean * mean;
    float av = gf1[tid] * rsqrtf(var + EPS);
    aS[tid] = av; cS[tid] = bef1[tid] - mean * av;
  }
  __syncthreads();
  float acc = bt[0];
  #pragma unroll 4
  for (int cc = 0; cc < 64; cc++)
    acc += siluf_(fmaf(aS[cc], y2[tid * 64 + cc], cS[cc])) * Wt[cc];
  out[tid] = acc;
}

// ---------------- host ----------------

extern "C" void kernel_launch(void* const* d_in, const int* in_sizes, int n_in,
                              void* d_out, int out_size, void* d_ws, size_t ws_size,
                              hipStream_t stream) {
  const float* node_feats = (const float*)d_in[0];
  const float* edge_feats = (const float*)d_in[1];
  const int* src = (const int*)d_in[2];
  const int* dst = (const int*)d_in[3];
  const int* gid = (const int*)d_in[4];
  const float* W_emb = (const float*)d_in[5];
  const float* g_emb = (const float*)d_in[7];
  const float* be_emb = (const float*)d_in[8];
  const float* Wm = (const float*)d_in[9];
  const float* gm = (const float*)d_in[11];
  const float* bem = (const float*)d_in[12];
  const float* Wsc = (const float*)d_in[13];
  const float* gs = (const float*)d_in[15];
  const float* bes = (const float*)d_in[16];
  const float* gn = (const float*)d_in[17];
  const float* ben = (const float*)d_in[18];
  const float* Wf0 = (const float*)d_in[19];
  const float* gf0 = (const float*)d_in[21];
  const float* bef0 = (const float*)d_in[22];
  const float* Wf1 = (const float*)d_in[23];
  const float* gf1 = (const float*)d_in[25];
  const float* bef1 = (const float*)d_in[26];
  const float* Wt = (const float*)d_in[27];
  const float* bt = (const float*)d_in[28];
  float* out = (float*)d_out;

  char* ws = (char*)d_ws;
  size_t off = 0;
  auto alloc = [&](size_t bytes) -> void* {
    void* p = ws + off;
    off = (off + bytes + 511) & ~(size_t)511;
    return p;
  };
  u16* ef_s   = (u16*)alloc((size_t)M_EDGES * 48 * 2);   // padded, bf16
  u16* ybuf   = (u16*)alloc((size_t)M_EDGES * 128 * 2);
  u16* Ptop   = (u16*)alloc((size_t)N_NODES * 128 * 2);  // bf16 tables
  u16* Pmid   = (u16*)alloc((size_t)N_NODES * 128 * 2);
  float* vbuf = (float*)alloc((size_t)N_NODES * 64 * 4);
  float* nbuf = (float*)alloc((size_t)N_NODES * 64 * 4);
  int* row_ptr = (int*)alloc((size_t)(N_NODES + 1) * 4);
  int* nexts   = (int*)alloc((size_t)N_NODES * 4);
  int* eid_s   = (int*)alloc((size_t)M_EDGES * 4);
  int* src_s   = (int*)alloc((size_t)M_EDGES * 4);
  int* dst_s   = (int*)alloc((size_t)M_EDGES * 4);
  int* bsum    = (int*)alloc(256 * 4);
  int* boffs   = (int*)alloc(256 * 4);
  float* stats = (float*)alloc((size_t)68736 * 4);
  (void)ws_size; (void)in_sizes; (void)n_in; (void)out_size;

  // stats region offsets (floats); [0,19200) zeroed each call
  float* emb_s1 = stats + 0;
  float* emb_s2 = stats + 64;
  float* ys1    = stats + 256;   // 3*128
  float* ys2    = stats + 640;
  float* as1    = stats + 1792;  // 3*64
  float* as2    = stats + 1984;
  float* pcnt   = stats + 2560;  // 256
  float* psum   = stats + 2816;  // 256*64, ends 19200
  float* rb1    = stats + 19584; // 256*128
  float* rb2    = stats + 52352; // 256*64

  // preprocessing
  zero_kernel<<<196, 256, 0, stream>>>(nexts, stats, N_NODES, 19200);
  hist_kernel<<<3125, 256, 0, stream>>>(dst, nexts);
  scanA_kernel<<<196, 256, 0, stream>>>(nexts, bsum);
  scanB_kernel<<<1, 256, 0, stream>>>(bsum, boffs, row_ptr);
  scanC_kernel<<<196, 256, 0, stream>>>(nexts, boffs, row_ptr, nexts);
  scatter_kernel<<<3125, 256, 0, stream>>>(src, dst, nexts, eid_s, src_s, dst_s);
  permute_ef_kernel<<<25000, 256, 0, stream>>>(edge_feats, eid_s, ef_s);

  // embedding
  emb_mm_kernel<<<3125, 256, 0, stream>>>(node_feats, W_emb, nbuf);
  colstats64_kernel<<<200, 256, 0, stream>>>(nbuf, N_NODES, emb_s1, emb_s2);
  emb_apply_kernel<<<12500, 256, 0, stream>>>(nbuf, emb_s1, emb_s2, g_emb, be_emb, vbuf);

  for (int l = 0; l < NL; l++) {
    const float* Wm_l = Wm + (size_t)l * 169 * 64;
    const float* Ws_l = Wsc + (size_t)l * 169 * 64;
    ptab_kernel<<<6250, 256, 0, stream>>>(vbuf, Wm_l, Ws_l, Ptop, Pmid);
    edge_mm_kernel<<<1250, 256, 0, stream>>>(src_s, dst_s, ef_s, Ptop, Pmid,
                                             Wm_l, Ws_l, ybuf,
                                             ys1 + l * 128, ys2 + l * 128);
    aggregate_kernel<<<12500, 256, 0, stream>>>(ybuf, row_ptr, ys1 + l * 128, ys2 + l * 128,
                                                gm + l * 64, bem + l * 64,
                                                gs + l * 64, bes + l * 64, nbuf);
    colstats64_kernel<<<200, 256, 0, stream>>>(nbuf, N_NODES, as1 + l * 64, as2 + l * 64);
    node_update_kernel<<<12500, 256, 0, stream>>>(nbuf, as1 + l * 64, as2 + l * 64,
                                                  gn + l * 64, ben + l * 64, vbuf);
  }

  // pooling + readout
  pool_sum_kernel<<<196, 256, 0, stream>>>(vbuf, gid, psum, pcnt);
  ro_mm1_kernel<<<32, 256, 0, stream>>>(psum, pcnt, Wf0, rb1);
  ro_mm2_kernel<<<16, 256, 0, stream>>>(rb1, gf0, bef0, Wf1, rb2);
  ro_out_kernel<<<1, 256, 0, stream>>>(rb2, gf1, bef1, Wt, bt, out);
}